// Round 3
// baseline (30.628 us; speedup 1.0000x reference)
//
#include <hip/hip_runtime.h>

#define Bq 32
#define Jq 16
#define Hq 256
#define Wq 256
#define Cn 7
#define HW (Hq * Wq)          // 65536 per (b,j)
#define NBJ (Bq * Jq)         // 512 (b,j) pairs
#define SPLIT 2               // blocks per (b,j)
#define NBLK (NBJ * SPLIT)    // 1024 blocks -> 4 blocks/CU
#define TPB 256
#define HALF (HW / SPLIT)     // 32768 floats per block
#define V4PT (HALF / 4 / TPB) // 32 float4 per thread
#define BATCH 8               // loads in flight per thread

__global__ __launch_bounds__(TPB) void labelloss_argmax_kernel(
    const float* __restrict__ heatmap,
    float* __restrict__ wsv,
    int*   __restrict__ wsi)
{
    const int bid  = blockIdx.x;       // 0..1023
    const int bj   = bid >> 1;
    const int half = bid & 1;
    const int tid  = threadIdx.x;

    const float4* hm = (const float4*)(heatmap + (size_t)bj * HW + (size_t)half * HALF);

    float best = -3.402823466e+38f;
    int   bidx = 0x7fffffff;           // flat idx within the (b,j) slice

    #pragma unroll
    for (int bt = 0; bt < V4PT / BATCH; ++bt) {
        float4 v[BATCH];
        // Issue all BATCH 1KB wave-loads before any compare -> 8 in flight.
        #pragma unroll
        for (int u = 0; u < BATCH; ++u)
            v[u] = hm[(bt * BATCH + u) * TPB + tid];
        #pragma unroll
        for (int u = 0; u < BATCH; ++u) {
            const int base = ((bt * BATCH + u) * TPB + tid) * 4 + half * HALF;
            // Strict '>' keeps earliest index (thread scans increasing idx).
            if (v[u].x > best) { best = v[u].x; bidx = base;     }
            if (v[u].y > best) { best = v[u].y; bidx = base + 1; }
            if (v[u].z > best) { best = v[u].z; bidx = base + 2; }
            if (v[u].w > best) { best = v[u].w; bidx = base + 3; }
        }
    }

    // Wave-64 shuffle reduce; ties -> smaller flat index.
    #pragma unroll
    for (int off = 32; off > 0; off >>= 1) {
        const float ov = __shfl_down(best, off);
        const int   oi = __shfl_down(bidx, off);
        if (ov > best || (ov == best && oi < bidx)) { best = ov; bidx = oi; }
    }

    __shared__ float sval[TPB / 64];
    __shared__ int   sidx[TPB / 64];
    const int wave = tid >> 6;
    const int lane = tid & 63;
    if (lane == 0) { sval[wave] = best; sidx[wave] = bidx; }
    __syncthreads();

    if (tid == 0) {
        #pragma unroll
        for (int w = 1; w < TPB / 64; ++w) {
            if (sval[w] > best || (sval[w] == best && sidx[w] < bidx)) {
                best = sval[w]; bidx = sidx[w];
            }
        }
        wsv[bid] = best;
        wsi[bid] = bidx;
    }
}

// Merge the SPLIT candidates per (b,j), compute the masked class loss,
// and reduce the 16 joints per batch entry. One block, deterministic.
__global__ __launch_bounds__(NBJ) void labelloss_finish_kernel(
    const float* __restrict__ pred,
    const float* __restrict__ gt,
    const float* __restrict__ wsv,
    const int*   __restrict__ wsi,
    float* __restrict__ out)
{
    __shared__ float sloss[NBJ];
    const int bj = threadIdx.x;        // 0..511
    const int b  = bj >> 4;

    float best = wsv[bj * 2];
    int   bidx = wsi[bj * 2];
    const float v1 = wsv[bj * 2 + 1];
    const int   i1 = wsi[bj * 2 + 1];
    // half-1 indices are all > half-0 indices, so idx tie-break is exact
    if (v1 > best || (v1 == best && i1 < bidx)) { best = v1; bidx = i1; }

    float loss = 0.0f;
    if (best == 1.0f) {
        const int x = bidx >> 8;       // idx / 256
        const int y = bidx & 255;      // idx % 256
        const float* gp = gt + (size_t)bj * Cn;
        #pragma unroll
        for (int c = 0; c < Cn; ++c) {
            const float pv = pred[(((size_t)b * Cn + c) * Hq + x) * Wq + y];
            const float d  = pv - gp[c];
            loss += d * d;
        }
    }
    sloss[bj] = loss;
    __syncthreads();

    if (bj < Bq) {
        float s = 0.0f;
        #pragma unroll
        for (int j = 0; j < Jq; ++j) s += sloss[bj * Jq + j];
        out[bj] = s;                   // all 32 outputs written unconditionally
    }
}

extern "C" void kernel_launch(void* const* d_in, const int* in_sizes, int n_in,
                              void* d_out, int out_size, void* d_ws, size_t ws_size,
                              hipStream_t stream)
{
    const float* pred    = (const float*)d_in[0];   // (B, C, H, W) f32
    const float* gt      = (const float*)d_in[1];   // (B, J, C)   f32
    const float* heatmap = (const float*)d_in[2];   // (B, J, H, W) f32
    float* out = (float*)d_out;                     // (B,) f32
    float* wsv = (float*)d_ws;                      // NBLK floats
    int*   wsi = (int*)((char*)d_ws + NBLK * sizeof(float));

    labelloss_argmax_kernel<<<NBLK, TPB, 0, stream>>>(heatmap, wsv, wsi);
    labelloss_finish_kernel<<<1, NBJ, 0, stream>>>(pred, gt, wsv, wsi, out);
}